// Round 11
// baseline (185.310 us; speedup 1.0000x reference)
//
#include <hip/hip_runtime.h>

// ANI loss: per-voxel 3x3 symmetric eigen (closed form), masked L1 reduction.
// input_data [4,6,96,96,96] f32, target [4,6,96,96,96] f32, mask [4,1,96,96,96] i32,
// gt_mean [6] f32, gt_std [6] f32  ->  scalar f32 loss.
//
// R11 == R10 intent (nt + dwordx4), fixed compile: __builtin_nontemporal_load
// rejects HIP_vector_type (float4/int4) pointers but accepts clang
// ext_vector_type. R9 (nt scalar dword) broke the 65us wall -> ~51us
// (~3.5 TB/s): L2-allocation overhead was ~25% of the cap. fillBuffer runs
// 6.8 TB/s on the same fabric => headroom. Suspect: per-vmem-instruction
// overhead in TA/TCP (R9 = 13 dword loads/thread, 256B/wave-instr). Here:
// 4 voxels/thread, 13 nt dwordx4 loads (1KB/wave-instr, 4x fewer vmem
// instrs). Register chunking irrelevant in a rate-bound regime (R8: 28x MLP
// gained 0%).

namespace {
constexpr int SB    = 96 * 96 * 96;   // voxels per volume = 884736
constexpr int BATCH = 4;
constexpr int NVOX  = SB * BATCH;     // 3538944
constexpr int N4    = NVOX / 4;       // 884736 float4-groups
constexpr int BLOCK = 256;
constexpr int GRID  = N4 / BLOCK;     // 3456 blocks (exact)
constexpr int BLOCK2 = 1024;

typedef float fx4 __attribute__((ext_vector_type(4)));
typedef int   ix4 __attribute__((ext_vector_type(4)));

// Returns p*cos(acos(r)/3); q via out-param. Branchless, NaN-free.
__device__ __forceinline__ float eig_pc(const float y0, const float y1, const float y2,
                                        const float y3, const float y4, const float y5,
                                        float& q_out) {
    const float q  = (y0 + y3 + y5) * (1.0f / 3.0f);
    const float d0 = y0 - q, d1 = y3 - q, d2 = y5 - q;
    float p2 = d0 * d0;
    p2 = fmaf(d1, d1, p2);
    p2 = fmaf(d2, d2, p2);
    float c2 = y1 * y1;
    c2 = fmaf(y2, y2, c2);
    c2 = fmaf(y4, y4, c2);
    p2 = fmaf(2.0f, c2, p2);
    const float p2s = p2 * (1.0f / 6.0f);
    const float inv = rsqrtf(fmaxf(p2s, 1e-12f));  // 1/p (guarded)
    const float p   = p2s * inv;                   // = sqrt(p2s); ~0 when guarded

    // det(A - qI), unnormalized
    const float m0 = fmaf(d1, d2, -(y4 * y4));
    const float m1 = fmaf(y1, d2, -(y4 * y2));
    const float m2 = fmaf(y1, y4, -(d1 * y2));
    float det = d0 * m0;
    det = fmaf(-y1, m1, det);
    det = fmaf( y2, m2, det);

    float r = 0.5f * det * (inv * inv * inv);
    r = fminf(fmaxf(r, -1.0f + 1e-7f), 1.0f - 1e-7f);

    // acos(r) = r>=0 ?  sqrt(1-r)*P(r)  :  pi - sqrt(1+r)*P(-r)   (A&S 4.4.45)
    const float a  = fabsf(r);
    const float sq = sqrtf(1.0f - a);
    float poly = fmaf(a, -0.0187293f, 0.0742610f);
    poly = fmaf(a, poly, -0.2121144f);
    poly = fmaf(a, poly, 1.5707288f);
    const float t  = sq * poly;
    const float th = (r < 0.0f) ? (3.14159265358979f - t) : t;
    const float phi = th * (1.0f / 3.0f);

    // cos(phi), phi in [0, pi/3]
    const float u = phi * phi;
    float c = fmaf(u, 2.4801587e-5f, -1.3888889e-3f);
    c = fmaf(u, c, 4.16666679e-2f);
    c = fmaf(u, c, -0.5f);
    c = fmaf(u, c, 1.0f);

    q_out = q;
    return p * c;
}

__global__ __launch_bounds__(BLOCK) void ani_reduce(
    const float* __restrict__ in, const float* __restrict__ tg,
    const int*  __restrict__ mask,
    const float* __restrict__ gt_mean, const float* __restrict__ gt_std,
    float* __restrict__ ws) {

    float st[6], mn[6];
#pragma unroll
    for (int c = 0; c < 6; ++c) { st[c] = gt_std[c]; mn[c] = gt_mean[c]; }

    float sum_abs = 0.0f;
    float sum_m   = 0.0f;

    const int i  = blockIdx.x * blockDim.x + threadIdx.x;  // one float4-group
    const int v4 = i * 4;
    const int b  = v4 / SB;
    const int s  = v4 - b * SB;          // multiple of 4 -> 16B aligned
    const int base = (b * 6) * SB + s;

    // ---- 13 non-temporal dwordx4 loads (nt: no cache allocation) ----
    fx4 xi[6], xt[6];
#pragma unroll
    for (int c = 0; c < 6; ++c) {
        xi[c] = __builtin_nontemporal_load((const fx4*)(in + base + c * SB));
        xt[c] = __builtin_nontemporal_load((const fx4*)(tg + base + c * SB));
    }
    ix4 mk = __builtin_nontemporal_load((const ix4*)(mask + b * SB + s));

#pragma unroll
    for (int j = 0; j < 4; ++j) {
        float mf = (float)mk[j];
        float yi[6], yt[6];
#pragma unroll
        for (int c = 0; c < 6; ++c) {
            yi[c] = fmaf(xi[c][j], st[c], mn[c]);   // mask NOT applied
            yt[c] = fmaf(xt[c][j], st[c], mn[c]);
        }
        float qi, qt;
        float pci = eig_pc(yi[0], yi[1], yi[2], yi[3], yi[4], yi[5], qi);
        float pct = eig_pc(yt[0], yt[1], yt[2], yt[3], yt[4], yt[5], qt);
        float ani_in = 3.0f * pci;          // i2 - 0.5*(i0+i1)
        float ani_tg = qt - pct;            // 0.5*(t0+t1)
        sum_abs = fmaf(fabsf(ani_in - ani_tg), mf, sum_abs);
        sum_m  += mf;
    }

    // wave-64 reduction
#pragma unroll
    for (int off = 32; off > 0; off >>= 1) {
        sum_abs += __shfl_down(sum_abs, off, 64);
        sum_m   += __shfl_down(sum_m,   off, 64);
    }
    __shared__ float s_abs[BLOCK / 64];
    __shared__ float s_m[BLOCK / 64];
    int lane = threadIdx.x & 63;
    int wid  = threadIdx.x >> 6;
    if (lane == 0) { s_abs[wid] = sum_abs; s_m[wid] = sum_m; }
    __syncthreads();
    if (threadIdx.x == 0) {
        float ta = 0.0f, tm = 0.0f;
#pragma unroll
        for (int w = 0; w < BLOCK / 64; ++w) { ta += s_abs[w]; tm += s_m[w]; }
        // Uncontended per-block partial stores (no atomics).
        ws[blockIdx.x]        = ta;
        ws[GRID + blockIdx.x] = tm;
    }
}

__global__ __launch_bounds__(BLOCK2) void ani_stage2(
    const float* __restrict__ ws, float* __restrict__ out) {
    float sa = 0.0f, sm = 0.0f;
    for (int i = threadIdx.x; i < GRID; i += BLOCK2) {
        sa += ws[i];
        sm += ws[GRID + i];
    }
#pragma unroll
    for (int off = 32; off > 0; off >>= 1) {
        sa += __shfl_down(sa, off, 64);
        sm += __shfl_down(sm, off, 64);
    }
    __shared__ float s_abs[BLOCK2 / 64];
    __shared__ float s_m[BLOCK2 / 64];
    int lane = threadIdx.x & 63;
    int wid  = threadIdx.x >> 6;
    if (lane == 0) { s_abs[wid] = sa; s_m[wid] = sm; }
    __syncthreads();
    if (threadIdx.x == 0) {
        float ta = 0.0f, tm = 0.0f;
#pragma unroll
        for (int w = 0; w < BLOCK2 / 64; ++w) { ta += s_abs[w]; tm += s_m[w]; }
        out[0] = ta / fmaxf(tm, 1.0f);
    }
}

} // namespace

extern "C" void kernel_launch(void* const* d_in, const int* in_sizes, int n_in,
                              void* d_out, int out_size, void* d_ws, size_t ws_size,
                              hipStream_t stream) {
    const float* in      = (const float*)d_in[0];
    const float* tg      = (const float*)d_in[1];
    const int*   mask    = (const int*)d_in[2];
    const float* gt_mean = (const float*)d_in[3];
    const float* gt_std  = (const float*)d_in[4];
    float* ws  = (float*)d_ws;   // needs 2*GRID floats = 27.6 KB
    float* out = (float*)d_out;

    ani_reduce<<<GRID, BLOCK, 0, stream>>>(in, tg, mask, gt_mean, gt_std, ws);
    ani_stage2<<<1, BLOCK2, 0, stream>>>(ws, out);
}